// Round 4
// baseline (209.319 us; speedup 1.0000x reference)
//
#include <hip/hip_runtime.h>

// B=4, S=1024, E=1024, H=16, D=64. All GEMMs are 4096x1024x1024 (A MxK row-major,
// W NxK row-major => C = A * W^T + bias).

typedef _Float16 v8h __attribute__((ext_vector_type(8)));
typedef _Float16 v4h __attribute__((ext_vector_type(4)));
typedef _Float16 v2h __attribute__((ext_vector_type(2)));
typedef float    v4f __attribute__((ext_vector_type(4)));

#define MFMA_F16(A_, B_, C_) __builtin_amdgcn_mfma_f32_16x16x32_f16(A_, B_, C_, 0, 0, 0)

__device__ __forceinline__ void async_copy16(const void* g, void* l) {
    __builtin_amdgcn_global_load_lds(
        (const __attribute__((address_space(1))) void*)g,
        (__attribute__((address_space(3))) void*)l, 16, 0, 0);
}

// ---------------- fp32 -> fp16 conversion (5 tensors, one launch) ----------------
__global__ __launch_bounds__(256) void cvt5_kernel(
    const float* __restrict__ s0, const float* __restrict__ s1,
    const float* __restrict__ s2, const float* __restrict__ s3,
    const float* __restrict__ s4,
    _Float16* __restrict__ d0, _Float16* __restrict__ d1,
    _Float16* __restrict__ d2, _Float16* __restrict__ d3,
    _Float16* __restrict__ d4,
    int n0, int n1, int n2, int n3, int n4)
{
    const float* s; _Float16* d; int n;
    switch (blockIdx.y) {
        case 0:  s = s0; d = d0; n = n0; break;
        case 1:  s = s1; d = d1; n = n1; break;
        case 2:  s = s2; d = d2; n = n2; break;
        case 3:  s = s3; d = d3; n = n3; break;
        default: s = s4; d = d4; n = n4; break;
    }
    int i = (blockIdx.x * 256 + threadIdx.x) * 4;
    if (i >= n) return;
    float4 f = *(const float4*)(s + i);
    v4h o = { (_Float16)f.x, (_Float16)f.y, (_Float16)f.z, (_Float16)f.w };
    *(v4h*)(d + i) = o;
}

// ---------------- shared GEMM core: C = A * W^T + bias ----------------
// TM x 128 tile, BK=64, 256 threads. XOR-swizzled LDS (16B chunk c of row r holds
// logical chunk c ^ (r&7)); staged via global_load_lds 16B/lane. Epilogue goes
// through per-wave 8KB LDS scratch so all global stores are coalesced 16B/lane.
// mode 0: fp16 (B,H,S,D); mode 1: fp16 transposed (B,H,D,S); mode 2: fp32 (M,N).
template<int TM>
__device__ __forceinline__ void gemm_core(const _Float16* __restrict__ A,
                                          const _Float16* __restrict__ W,
                                          const float* __restrict__ bias,
                                          int mode, void* __restrict__ outp)
{
    __shared__ __align__(16) _Float16 smem[2 * 128 * 64];   // As | Bs, 32 KB
    _Float16* As = smem;
    _Float16* Bs = smem + 128 * 64;

    const int tid  = threadIdx.x;
    const int wave = tid >> 6, lane = tid & 63;
    const int quad = lane >> 4, n16 = lane & 15;
    const int wm = (TM == 128) ? (wave >> 1) : 0;
    const int wn = (TM == 128) ? (wave & 1) : wave;
    const int WCOLS = (TM == 128) ? 64 : 32;
    const int NJ = WCOLS / 16;
    const int row0 = blockIdx.y * TM, col0 = blockIdx.x * 128;
    const int rL = lane >> 3, c8 = lane & 7;
    const int lcs = c8 ^ rL;

    v4f acc[4][4] = {};

    for (int kb = 0; kb < 1024; kb += 64) {
        __syncthreads();
        #pragma unroll
        for (int p = 0; p < TM / 32; p++) {
            int rg = wave * (TM / 32) + p;
            int row = rg * 8 + rL;
            async_copy16(A + (size_t)(row0 + row) * 1024 + kb + lcs * 8, &As[rg * 512]);
        }
        #pragma unroll
        for (int p = 0; p < 4; p++) {
            int rg = wave * 4 + p;
            int row = rg * 8 + rL;
            async_copy16(W + (size_t)(col0 + row) * 1024 + kb + lcs * 8, &Bs[rg * 512]);
        }
        __syncthreads();
        #pragma unroll
        for (int ks = 0; ks < 64; ks += 32) {
            const int pc = ((ks >> 3) + quad) ^ (n16 & 7);
            v8h af[4], bf[4];
            #pragma unroll
            for (int i = 0; i < 4; i++)
                af[i] = *(const v8h*)(&As[(wm * 64 + i * 16 + n16) * 64 + pc * 8]);
            #pragma unroll
            for (int j = 0; j < NJ; j++)
                bf[j] = *(const v8h*)(&Bs[(wn * WCOLS + j * 16 + n16) * 64 + pc * 8]);
            #pragma unroll
            for (int i = 0; i < 4; i++)
                #pragma unroll
                for (int j = 0; j < NJ; j++)
                    acc[i][j] = MFMA_F16(af[i], bf[j], acc[i][j]);
        }
    }

    __syncthreads();                       // staged tiles dead; reuse LDS as scratch
    char* scb = (char*)smem + wave * 8192; // per-wave 8 KB

    const int b     = (row0 + wm * 64) >> 10;
    const int srow0 = (row0 + wm * 64) & 1023;

    if (mode == 0) {                       // [s][d] scratch, coalesced (B,H,S,D) stores
        _Float16* sc = (_Float16*)scb;
        #pragma unroll
        for (int i = 0; i < 4; i++)
            #pragma unroll
            for (int j = 0; j < 4; j++)
                #pragma unroll
                for (int r = 0; r < 4; r++) {
                    int rowL = i * 16 + quad * 4 + r, colL = j * 16 + n16;
                    float v = acc[i][j][r] + bias[col0 + wn * 64 + colL];
                    sc[rowL * 64 + (((colL >> 3) ^ (rowL & 7)) << 3) + (colL & 7)] = (_Float16)v;
                }
        int h = (col0 + wn * 64) >> 6;
        #pragma unroll
        for (int it = 0; it < 8; it++) {
            int rowR = it * 8 + (lane >> 3), cR = lane & 7;
            v8h val = *(const v8h*)(&sc[rowR * 64 + ((cR ^ (rowR & 7)) << 3)]);
            *(v8h*)((_Float16*)outp +
                    (((size_t)(b * 16 + h) * 1024 + srow0 + rowR) << 6) + cR * 8) = val;
        }
    } else if (mode == 1) {                // [d][s] scratch, coalesced (B,H,D,S) stores
        _Float16* sc = (_Float16*)scb;
        #pragma unroll
        for (int i = 0; i < 4; i++)
            #pragma unroll
            for (int j = 0; j < 4; j++) {
                int colL = j * 16 + n16;
                int c16 = i * 2 + (quad >> 1);
                v4h pk;
                #pragma unroll
                for (int r = 0; r < 4; r++)
                    pk[r] = (_Float16)(acc[i][j][r] + bias[col0 + wn * 64 + colL]);
                *(v4h*)(&sc[colL * 64 + ((c16 ^ (colL & 7)) << 3) + (quad & 1) * 4]) = pk;
            }
        #pragma unroll
        for (int it = 0; it < 8; it++) {
            int dR = it * 8 + (lane >> 3), scn = lane & 7;
            v8h val = *(const v8h*)(&sc[dR * 64 + ((scn ^ (dR & 7)) << 3)]);
            int cg = col0 + wn * 64 + dR;
            int h = cg >> 6, dl = cg & 63;
            *(v8h*)((_Float16*)outp +
                    ((size_t)((b * 16 + h) * 64 + dl) << 10) + srow0 + scn * 8) = val;
        }
    } else {                               // mode 2 (TM=64): fp32 [m][n], wave tile 64x32
        float* sc = (float*)scb;
        #pragma unroll
        for (int i = 0; i < 4; i++)
            #pragma unroll
            for (int j = 0; j < 2; j++)
                #pragma unroll
                for (int r = 0; r < 4; r++) {
                    int rowL = i * 16 + quad * 4 + r, colL = j * 16 + n16;
                    sc[rowL * 32 + (((colL >> 2) ^ (rowL & 7)) << 2) + (colL & 3)] =
                        acc[i][j][r] + bias[col0 + wn * 32 + colL];
                }
        #pragma unroll
        for (int it = 0; it < 8; it++) {
            int rowR = it * 8 + (lane >> 3), cR = lane & 7;
            v4f val = *(const v4f*)(&sc[rowR * 32 + ((cR ^ (rowR & 7)) << 2)]);
            *(v4f*)((float*)outp + (size_t)(row0 + rowR) * 1024 + col0 + wn * 32 + cR * 4) = val;
        }
    }
}

__global__ __launch_bounds__(256) void gemm_qv_kernel(
    const _Float16* __restrict__ Aq, const _Float16* __restrict__ Av,
    const _Float16* __restrict__ Wq, const _Float16* __restrict__ Wv,
    const float* __restrict__ bq, const float* __restrict__ bv,
    _Float16* __restrict__ q_out, _Float16* __restrict__ v_out)
{
    int z = blockIdx.z;
    gemm_core<128>(z ? Av : Aq, z ? Wv : Wq, z ? bv : bq, z ? 1 : 0,
                   z ? (void*)v_out : (void*)q_out);
}

__global__ __launch_bounds__(256) void gemm_o_kernel(
    const _Float16* __restrict__ A, const _Float16* __restrict__ W,
    const float* __restrict__ bias, float* __restrict__ outp)
{
    gemm_core<64>(A, W, bias, 2, (void*)outp);
}

// ---------------- fused attention (S^T, static-max softmax, K == Q) -------------
// Block: 64 q-rows (4 waves x 16). 1-D grid: bh = blk&63 (XCD-local), qtile = blk>>6.
// Double-buffered K/V staging (prefetch tile i+1 before computing tile i, one
// barrier per iter). P's C-layout -> B-fragment exchange done in-register with
// ds_bpermute (__shfl) — zero LDS bank conflicts, no extra barrier.
__global__ __launch_bounds__(256) void attn_kernel(
    const _Float16* __restrict__ qb,   // (B,H,S,D) fp16
    const _Float16* __restrict__ vt,   // (B,H,D,S) fp16 (transposed)
    const float* __restrict__ rpk, const float* __restrict__ rpv,  // (5,64) fp32
    _Float16* __restrict__ attn_o)     // (B*S, H*D) fp16
{
    const int blk = blockIdx.x;
    const int bh = blk & 63;
    const int q0 = (blk >> 6) * 64;
    const int tid = threadIdx.x;
    const int wave = tid >> 6, lane = tid & 63;
    const int quad = lane >> 4, n16 = lane & 15;
    const int qw = q0 + wave * 16;
    const _Float16* Qh = qb + (size_t)bh * 1024 * 64;
    const _Float16* Vh = vt + (size_t)bh * 64 * 1024;

    __shared__ __align__(16) _Float16 Ks[2][64 * 64];
    __shared__ __align__(16) _Float16 Vs[2][64 * 64];
    __shared__ float rqs[4][16][5];

    const int rL = lane >> 3, c8 = lane & 7;
    const int lcs = c8 ^ rL;

    // prologue: stage tile 0 into buffer 0 (overlaps with rc precompute below)
    {
        #pragma unroll
        for (int p = 0; p < 2; p++) {
            int c = wave * 2 + p;
            int row = c * 8 + rL;
            async_copy16(Qh + (size_t)row * 64 + lcs * 8, &Ks[0][c * 512]);
            async_copy16(Vh + (size_t)row * 1024 + lcs * 8, &Vs[0][c * 512]);
        }
    }

    // rc[t] = (dot(q_row, rpk[t]) - |q_row|^2) * 0.125 for this lane's own q-row
    {
        int m = lane >> 2, seg = lane & 3;
        const _Float16* qrow = Qh + (size_t)(qw + m) * 64 + seg * 16;
        v8h qa = *(const v8h*)(qrow);
        v8h qc = *(const v8h*)(qrow + 8);
        float qd[16];
        #pragma unroll
        for (int x = 0; x < 8; x++) { qd[x] = (float)qa[x]; qd[8 + x] = (float)qc[x]; }
        float qq = 0.f;
        #pragma unroll
        for (int x = 0; x < 16; x++) qq += qd[x] * qd[x];
        qq += __shfl_xor(qq, 1);
        qq += __shfl_xor(qq, 2);
        #pragma unroll
        for (int t = 0; t < 5; t++) {
            float s = 0.f;
            #pragma unroll
            for (int x = 0; x < 16; x++) s += qd[x] * rpk[t * 64 + seg * 16 + x];
            s += __shfl_xor(s, 1);
            s += __shfl_xor(s, 2);
            if (seg == 0) rqs[wave][m][t] = (s - qq) * 0.125f;
        }
    }

    // Q fragment (B-operand): B[n=q=lane&15][k=quad*8+j]
    v8h aq0 = *(const v8h*)(Qh + (size_t)(qw + n16) * 64 + quad * 8);
    v8h aq1 = *(const v8h*)(Qh + (size_t)(qw + n16) * 64 + 32 + quad * 8);

    __syncthreads();   // drains tile-0 staging AND makes rqs visible

    float rc[5];
    #pragma unroll
    for (int t = 0; t < 5; t++) rc[t] = rqs[wave][n16][t];

    // bucket sums for this lane's q-row (index = rpk/rpv table row):
    // 4: diff>=2, 3: diff==1, 2: diff==0, 1: diff==-1, 0: diff<=-2
    float bkt[5] = {0.f, 0.f, 0.f, 0.f, 0.f};
    v4f O[4] = {};

    const int pphys0 = quad ^ (n16 & 7);
    const int pphys1 = (quad + 4) ^ (n16 & 7);
    // shfl sources for the P exchange: lanes {2*(quad&1), 2*(quad&1)+1} * 16 + n16
    const int srcA = ((quad & 1) << 5) + n16;
    const int srcB = srcA + 16;
    const bool tHi = (quad >> 1) != 0;

    for (int it = 0; it < 16; ++it) {
        const int cur = it & 1;
        const int kb = it * 64;
        if (it + 1 < 16) {                 // prefetch next tile into other buffer
            const int nxt = 1 - cur;
            const int kn = kb + 64;
            #pragma unroll
            for (int p = 0; p < 2; p++) {
                int c = wave * 2 + p;
                int row = c * 8 + rL;
                async_copy16(Qh + (size_t)(kn + row) * 64 + lcs * 8, &Ks[nxt][c * 512]);
                async_copy16(Vh + (size_t)row * 1024 + kn + lcs * 8, &Vs[nxt][c * 512]);
            }
        }

        // ---- scores S^T: lane owns q = qw+n16, k = t*16 + quad*4 + r ----
        int pkLo[4], pkHi[4];
        #pragma unroll
        for (int t = 0; t < 4; t++) {
            v8h ak0 = *(const v8h*)(&Ks[cur][(t * 16 + n16) * 64 + pphys0 * 8]);
            v8h ak1 = *(const v8h*)(&Ks[cur][(t * 16 + n16) * 64 + pphys1 * 8]);
            v4f s = {0.f, 0.f, 0.f, 0.f};
            s = MFMA_F16(ak0, aq0, s);
            s = MFMA_F16(ak1, aq1, s);
            const int dqt = qw - kb - t * 16;      // wave-uniform
            float pv[4];
            if (dqt >= 32) {                       // whole tile diff >= 2
                #pragma unroll
                for (int r = 0; r < 4; r++) {
                    float p = __expf(fmaf(s[r], 0.125f, rc[4]));
                    pv[r] = p; bkt[4] += p;
                }
            } else if (dqt <= -32) {               // whole tile diff <= -2
                #pragma unroll
                for (int r = 0; r < 4; r++) {
                    float p = __expf(fmaf(s[r], 0.125f, rc[0]));
                    pv[r] = p; bkt[0] += p;
                }
            } else {                               // near-diagonal tile
                #pragma unroll
                for (int r = 0; r < 4; r++) {
                    int diff = dqt + n16 - quad * 4 - r;
                    float rv = diff >= 2  ? rc[4]
                             : diff == 1  ? rc[3]
                             : diff == 0  ? rc[2]
                             : diff == -1 ? rc[1]
                                          : rc[0];
                    float p = __expf(fmaf(s[r], 0.125f, rv));
                    pv[r] = p;
                    bkt[4] += (diff >= 2)  ? p : 0.f;
                    bkt[3] += (diff == 1)  ? p : 0.f;
                    bkt[2] += (diff == 0)  ? p : 0.f;
                    bkt[1] += (diff == -1) ? p : 0.f;
                    bkt[0] += (diff <= -2) ? p : 0.f;
                }
            }
            pkLo[t] = __builtin_bit_cast(int, __builtin_amdgcn_cvt_pkrtz(pv[0], pv[1]));
            pkHi[t] = __builtin_bit_cast(int, __builtin_amdgcn_cvt_pkrtz(pv[2], pv[3]));
        }

        // ---- in-register P exchange: C-layout -> B-fragment (ds_bpermute) ----
        // lane needs dwords of P[q=n16][k=quad*8+j] (pf0) and k=32+quad*8+j (pf1)
        // from source lanes srcA/srcB at tile index t0 = quad>>1 (pf0), t0+2 (pf1).
        int aL0 = __shfl(pkLo[0], srcA), aH0 = __shfl(pkHi[0], srcA);
        int bL0 = __shfl(pkLo[0], srcB), bH0 = __shfl(pkHi[0], srcB);
        int aL1 = __shfl(pkLo[1], srcA), aH1 = __shfl(pkHi[1], srcA);
        int bL1 = __shfl(pkLo[1], srcB), bH1 = __shfl(pkHi[1], srcB);
        int aL2 = __shfl(pkLo[2], srcA), aH2 = __shfl(pkHi[2], srcA);
        int bL2 = __shfl(pkLo[2], srcB), bH2 = __shfl(pkHi[2], srcB);
        int aL3 = __shfl(pkLo[3], srcA), aH3 = __shfl(pkHi[3], srcA);
        int bL3 = __shfl(pkLo[3], srcB), bH3 = __shfl(pkHi[3], srcB);
        union { int d[4]; v8h v; } u0, u1;
        u0.d[0] = tHi ? aL1 : aL0;  u0.d[1] = tHi ? aH1 : aH0;
        u0.d[2] = tHi ? bL1 : bL0;  u0.d[3] = tHi ? bH1 : bH0;
        u1.d[0] = tHi ? aL3 : aL2;  u1.d[1] = tHi ? aH3 : aH2;
        u1.d[2] = tHi ? bL3 : bL2;  u1.d[3] = tHi ? bH3 : bH2;
        v8h pf0 = u0.v, pf1 = u1.v;

        #pragma unroll
        for (int dt = 0; dt < 4; dt++) {
            v8h av0 = *(const v8h*)(&Vs[cur][(dt * 16 + n16) * 64 + pphys0 * 8]);
            v8h av1 = *(const v8h*)(&Vs[cur][(dt * 16 + n16) * 64 + pphys1 * 8]);
            O[dt] = MFMA_F16(av0, pf0, O[dt]);    // O^T: row = d-local, col = q
            O[dt] = MFMA_F16(av1, pf1, O[dt]);
        }

        __syncthreads();   // drains prefetch (had full compute to fly) + buffer reuse
    }

    // epilogue: reduce buckets across the 4 quads sharing this q-row
    #pragma unroll
    for (int t = 0; t < 5; t++) {
        bkt[t] += __shfl_xor(bkt[t], 16);
        bkt[t] += __shfl_xor(bkt[t], 32);
    }
    float l = bkt[0] + bkt[1] + bkt[2] + bkt[3] + bkt[4];
    float inv = 1.0f / l;
    int q = qw + n16;
    size_t orow = (size_t)((bh >> 4) * 1024 + q) * 1024 + (bh & 15) * 64;
    #pragma unroll
    for (int dt = 0; dt < 4; dt++) {
        int d0 = dt * 16 + quad * 4;
        v4h st;
        #pragma unroll
        for (int r = 0; r < 4; r++) {
            int d = d0 + r;
            float w2 = bkt[4] * rpv[4 * 64 + d] + bkt[3] * rpv[3 * 64 + d]
                     + bkt[2] * rpv[2 * 64 + d] + bkt[1] * rpv[1 * 64 + d]
                     + bkt[0] * rpv[0 * 64 + d];
            st[r] = (_Float16)((O[dt][r] + w2) * inv);
        }
        *(v4h*)(attn_o + orow + d0) = st;
    }
}

// ---------------- host launcher ----------------
extern "C" void kernel_launch(void* const* d_in, const int* in_sizes, int n_in,
                              void* d_out, int out_size, void* d_ws, size_t ws_size,
                              hipStream_t stream)
{
    const float* query = (const float*)d_in[0];
    // d_in[1] = key (unused: reference's k projection is dead code)
    const float* value = (const float*)d_in[2];
    const float* Wq = (const float*)d_in[3];
    const float* bq = (const float*)d_in[4];
    // d_in[5], d_in[6] = Wk, bk (unused)
    const float* Wv = (const float*)d_in[7];
    const float* bv = (const float*)d_in[8];
    const float* Wo = (const float*)d_in[9];
    const float* bo = (const float*)d_in[10];
    const float* rpk = (const float*)d_in[11];
    const float* rpv = (const float*)d_in[12];
    float* out = (float*)d_out;

    char* ws = (char*)d_ws;
    const size_t MB = 1024 * 1024;
    _Float16* q_bhsd = (_Float16*)(ws);             // 8 MB: q proj (B,H,S,D)
    _Float16* v_t    = (_Float16*)(ws + 8 * MB);    // 8 MB: v proj (B,H,D,S)
    _Float16* q16    = (_Float16*)(ws + 16 * MB);   // 8 MB: query fp16
    _Float16* attn_o = (_Float16*)(ws + 16 * MB);   // aliases q16 (dead after gemm_qv)
    _Float16* v16    = (_Float16*)(ws + 24 * MB);   // 8 MB: value fp16
    _Float16* wq16   = (_Float16*)(ws + 32 * MB);   // 2 MB
    _Float16* wv16   = (_Float16*)(ws + 34 * MB);   // 2 MB
    _Float16* wo16   = (_Float16*)(ws + 36 * MB);   // 2 MB   (total 38 MB)

    cvt5_kernel<<<dim3(4096, 5), 256, 0, stream>>>(
        query, value, Wq, Wv, Wo, q16, v16, wq16, wv16, wo16,
        4096 * 1024, 4096 * 1024, 1024 * 1024, 1024 * 1024, 1024 * 1024);

    gemm_qv_kernel<<<dim3(8, 32, 2), 256, 0, stream>>>(
        q16, v16, wq16, wv16, bq, bv, q_bhsd, v_t);

    attn_kernel<<<dim3(1024), 256, 0, stream>>>(q_bhsd, v_t, rpk, rpv, attn_o);

    gemm_o_kernel<<<dim3(8, 64), 256, 0, stream>>>(attn_o, wo16, bo, out);
}

// Round 5
// 203.882 us; speedup vs baseline: 1.0267x; 1.0267x over previous
//
#include <hip/hip_runtime.h>

// B=4, S=1024, E=1024, H=16, D=64. All GEMMs are 4096x1024x1024 (A MxK row-major,
// W NxK row-major => C = A * W^T + bias).

typedef _Float16 v8h __attribute__((ext_vector_type(8)));
typedef _Float16 v4h __attribute__((ext_vector_type(4)));
typedef float    v4f __attribute__((ext_vector_type(4)));

#define MFMA_F16(A_, B_, C_) __builtin_amdgcn_mfma_f32_16x16x32_f16(A_, B_, C_, 0, 0, 0)

__device__ __forceinline__ void async_copy16(const void* g, void* l) {
    __builtin_amdgcn_global_load_lds(
        (const __attribute__((address_space(1))) void*)g,
        (__attribute__((address_space(3))) void*)l, 16, 0, 0);
}

// ---------------- fp32 -> fp16 conversion (5 tensors, one launch) ----------------
__global__ __launch_bounds__(256) void cvt5_kernel(
    const float* __restrict__ s0, const float* __restrict__ s1,
    const float* __restrict__ s2, const float* __restrict__ s3,
    const float* __restrict__ s4,
    _Float16* __restrict__ d0, _Float16* __restrict__ d1,
    _Float16* __restrict__ d2, _Float16* __restrict__ d3,
    _Float16* __restrict__ d4,
    int n0, int n1, int n2, int n3, int n4)
{
    const float* s; _Float16* d; int n;
    switch (blockIdx.y) {
        case 0:  s = s0; d = d0; n = n0; break;
        case 1:  s = s1; d = d1; n = n1; break;
        case 2:  s = s2; d = d2; n = n2; break;
        case 3:  s = s3; d = d3; n = n3; break;
        default: s = s4; d = d4; n = n4; break;
    }
    int i = (blockIdx.x * 256 + threadIdx.x) * 4;
    if (i >= n) return;
    float4 f = *(const float4*)(s + i);
    v4h o = { (_Float16)f.x, (_Float16)f.y, (_Float16)f.z, (_Float16)f.w };
    *(v4h*)(d + i) = o;
}

// ---------------- shared GEMM core: C = A * W^T + bias ----------------
// TM x 128 tile, BK=64, 256 threads. XOR-swizzled LDS (16B chunk c of row r holds
// logical chunk c ^ (r&7)); staged via global_load_lds 16B/lane. Epilogue goes
// through per-wave 8KB LDS scratch so all global stores are coalesced 16B/lane.
// mode 0: fp16 (B,H,S,D); mode 1: fp16 transposed (B,H,D,S); mode 2: fp32 (M,N).
template<int TM>
__device__ __forceinline__ void gemm_core(const _Float16* __restrict__ A,
                                          const _Float16* __restrict__ W,
                                          const float* __restrict__ bias,
                                          int mode, void* __restrict__ outp,
                                          int row0, int col0)
{
    __shared__ __align__(16) _Float16 smem[2 * 128 * 64];   // As | Bs, 32 KB
    _Float16* As = smem;
    _Float16* Bs = smem + 128 * 64;

    const int tid  = threadIdx.x;
    const int wave = tid >> 6, lane = tid & 63;
    const int quad = lane >> 4, n16 = lane & 15;
    const int wm = (TM == 128) ? (wave >> 1) : 0;
    const int wn = (TM == 128) ? (wave & 1) : wave;
    const int WCOLS = (TM == 128) ? 64 : 32;
    const int NJ = WCOLS / 16;
    const int rL = lane >> 3, c8 = lane & 7;
    const int lcs = c8 ^ rL;

    v4f acc[4][4] = {};

    for (int kb = 0; kb < 1024; kb += 64) {
        __syncthreads();
        #pragma unroll
        for (int p = 0; p < TM / 32; p++) {
            int rg = wave * (TM / 32) + p;
            int row = rg * 8 + rL;
            async_copy16(A + (size_t)(row0 + row) * 1024 + kb + lcs * 8, &As[rg * 512]);
        }
        #pragma unroll
        for (int p = 0; p < 4; p++) {
            int rg = wave * 4 + p;
            int row = rg * 8 + rL;
            async_copy16(W + (size_t)(col0 + row) * 1024 + kb + lcs * 8, &Bs[rg * 512]);
        }
        __syncthreads();
        #pragma unroll
        for (int ks = 0; ks < 64; ks += 32) {
            const int pc = ((ks >> 3) + quad) ^ (n16 & 7);
            v8h af[4], bf[4];
            #pragma unroll
            for (int i = 0; i < 4; i++)
                af[i] = *(const v8h*)(&As[(wm * 64 + i * 16 + n16) * 64 + pc * 8]);
            #pragma unroll
            for (int j = 0; j < NJ; j++)
                bf[j] = *(const v8h*)(&Bs[(wn * WCOLS + j * 16 + n16) * 64 + pc * 8]);
            #pragma unroll
            for (int i = 0; i < 4; i++)
                #pragma unroll
                for (int j = 0; j < NJ; j++)
                    acc[i][j] = MFMA_F16(af[i], bf[j], acc[i][j]);
        }
    }

    __syncthreads();                       // staged tiles dead; reuse LDS as scratch
    char* scb = (char*)smem + wave * 8192; // per-wave 8 KB

    const int b     = (row0 + wm * 64) >> 10;
    const int srow0 = (row0 + wm * 64) & 1023;

    if (mode == 0) {                       // [s][d] scratch, coalesced (B,H,S,D) stores
        _Float16* sc = (_Float16*)scb;
        #pragma unroll
        for (int i = 0; i < 4; i++)
            #pragma unroll
            for (int j = 0; j < 4; j++)
                #pragma unroll
                for (int r = 0; r < 4; r++) {
                    int rowL = i * 16 + quad * 4 + r, colL = j * 16 + n16;
                    float v = acc[i][j][r] + bias[col0 + wn * 64 + colL];
                    sc[rowL * 64 + (((colL >> 3) ^ (rowL & 7)) << 3) + (colL & 7)] = (_Float16)v;
                }
        int h = (col0 + wn * 64) >> 6;
        #pragma unroll
        for (int it = 0; it < 8; it++) {
            int rowR = it * 8 + (lane >> 3), cR = lane & 7;
            v8h val = *(const v8h*)(&sc[rowR * 64 + ((cR ^ (rowR & 7)) << 3)]);
            *(v8h*)((_Float16*)outp +
                    (((size_t)(b * 16 + h) * 1024 + srow0 + rowR) << 6) + cR * 8) = val;
        }
    } else if (mode == 1) {                // [d][s] scratch, coalesced (B,H,D,S) stores
        _Float16* sc = (_Float16*)scb;
        #pragma unroll
        for (int i = 0; i < 4; i++)
            #pragma unroll
            for (int j = 0; j < 4; j++) {
                int colL = j * 16 + n16;
                int c16 = i * 2 + (quad >> 1);
                v4h pk;
                #pragma unroll
                for (int r = 0; r < 4; r++)
                    pk[r] = (_Float16)(acc[i][j][r] + bias[col0 + wn * 64 + colL]);
                *(v4h*)(&sc[colL * 64 + ((c16 ^ (colL & 7)) << 3) + (quad & 1) * 4]) = pk;
            }
        #pragma unroll
        for (int it = 0; it < 8; it++) {
            int dR = it * 8 + (lane >> 3), scn = lane & 7;
            v8h val = *(const v8h*)(&sc[dR * 64 + ((scn ^ (dR & 7)) << 3)]);
            int cg = col0 + wn * 64 + dR;
            int h = cg >> 6, dl = cg & 63;
            *(v8h*)((_Float16*)outp +
                    ((size_t)((b * 16 + h) * 64 + dl) << 10) + srow0 + scn * 8) = val;
        }
    } else {                               // mode 2 (TM=64): fp32 [m][n], wave tile 64x32
        float* sc = (float*)scb;
        #pragma unroll
        for (int i = 0; i < 4; i++)
            #pragma unroll
            for (int j = 0; j < 2; j++)
                #pragma unroll
                for (int r = 0; r < 4; r++) {
                    int rowL = i * 16 + quad * 4 + r, colL = j * 16 + n16;
                    sc[rowL * 32 + (((colL >> 2) ^ (rowL & 7)) << 2) + (colL & 3)] =
                        acc[i][j][r] + bias[col0 + wn * 32 + colL];
                }
        #pragma unroll
        for (int it = 0; it < 8; it++) {
            int rowR = it * 8 + (lane >> 3), cR = lane & 7;
            v4f val = *(const v4f*)(&sc[rowR * 32 + ((cR ^ (rowR & 7)) << 2)]);
            *(v4f*)((float*)outp + (size_t)(row0 + rowR) * 1024 + col0 + wn * 32 + cR * 4) = val;
        }
    }
}

// 1-D grid, 512 blocks. XCD swizzle keyed on A row-strip: y%8 == id%8, so each
// XCD's A working set is 4 strips x 256KB x 2z = 2MB (fits per-XCD 4MB L2).
__global__ __launch_bounds__(256) void gemm_qv_kernel(
    const _Float16* __restrict__ Aq, const _Float16* __restrict__ Av,
    const _Float16* __restrict__ Wq, const _Float16* __restrict__ Wv,
    const float* __restrict__ bq, const float* __restrict__ bv,
    _Float16* __restrict__ q_out, _Float16* __restrict__ v_out)
{
    int id = blockIdx.x;
    int y = (id & 7) | (((id >> 3) & 3) << 3);   // 0..31
    int x = (id >> 5) & 7;                       // 0..7
    int z = id >> 8;                             // 0..1
    gemm_core<128>(z ? Av : Aq, z ? Wv : Wq, z ? bv : bq, z ? 1 : 0,
                   z ? (void*)v_out : (void*)q_out, y * 128, x * 128);
}

// 1-D grid, 512 blocks. Same row-strip-keyed XCD swizzle (y%8 == id%8).
__global__ __launch_bounds__(256) void gemm_o_kernel(
    const _Float16* __restrict__ A, const _Float16* __restrict__ W,
    const float* __restrict__ bias, float* __restrict__ outp)
{
    int id = blockIdx.x;
    int y = (id & 7) | (((id >> 3) & 7) << 3);   // 0..63
    int x = id >> 6;                             // 0..7
    gemm_core<64>(A, W, bias, 2, (void*)outp, y * 64, x * 128);
}

// ---------------- fused attention (S^T, static-max softmax, K == Q) -------------
// Block: 64 q-rows (4 waves x 16). 1-D grid: bh = blk&63 (XCD-local), qtile = blk>>6.
// Double-buffered K/V staging, ONE barrier per k-iter (prefetch for tile i+1 is
// issued before computing tile i; the barrier's vmcnt drain lands after compute).
// P goes C-layout -> per-wave LDS (swizzled v4h) -> B-fragment b128 reads.
__global__ __launch_bounds__(256) void attn_kernel(
    const _Float16* __restrict__ qb,   // (B,H,S,D) fp16
    const _Float16* __restrict__ vt,   // (B,H,D,S) fp16 (transposed)
    const float* __restrict__ rpk, const float* __restrict__ rpv,  // (5,64) fp32
    _Float16* __restrict__ attn_o)     // (B*S, H*D) fp16
{
    const int blk = blockIdx.x;
    const int bh = blk & 63;
    const int q0 = (blk >> 6) * 64;
    const int tid = threadIdx.x;
    const int wave = tid >> 6, lane = tid & 63;
    const int quad = lane >> 4, n16 = lane & 15;
    const int qw = q0 + wave * 16;
    const _Float16* Qh = qb + (size_t)bh * 1024 * 64;
    const _Float16* Vh = vt + (size_t)bh * 64 * 1024;

    __shared__ __align__(16) _Float16 Ks[2][64 * 64];
    __shared__ __align__(16) _Float16 Vs[2][64 * 64];
    __shared__ __align__(16) _Float16 Ps[4][16 * 64];   // rqs aliases Ps (dead after preload)

    const int rL = lane >> 3, c8 = lane & 7;
    const int lcs = c8 ^ rL;

    // prologue: stage tile 0 into buffer 0 (overlaps rc precompute below)
    #pragma unroll
    for (int p = 0; p < 2; p++) {
        int c = wave * 2 + p;
        int row = c * 8 + rL;
        async_copy16(Qh + (size_t)row * 64 + lcs * 8, &Ks[0][c * 512]);
        async_copy16(Vh + (size_t)row * 1024 + lcs * 8, &Vs[0][c * 512]);
    }

    // rc[t] = (dot(q_row, rpk[t]) - |q_row|^2) * 0.125 for this lane's own q-row.
    // Staged in Ps[wave] (read back into regs before any P write).
    float* rqs_w = (float*)&Ps[wave][0];
    {
        int m = lane >> 2, seg = lane & 3;
        const _Float16* qrow = Qh + (size_t)(qw + m) * 64 + seg * 16;
        v8h qa = *(const v8h*)(qrow);
        v8h qc = *(const v8h*)(qrow + 8);
        float qd[16];
        #pragma unroll
        for (int x = 0; x < 8; x++) { qd[x] = (float)qa[x]; qd[8 + x] = (float)qc[x]; }
        float qq = 0.f;
        #pragma unroll
        for (int x = 0; x < 16; x++) qq += qd[x] * qd[x];
        qq += __shfl_xor(qq, 1);
        qq += __shfl_xor(qq, 2);
        #pragma unroll
        for (int t = 0; t < 5; t++) {
            float s = 0.f;
            #pragma unroll
            for (int x = 0; x < 16; x++) s += qd[x] * rpk[t * 64 + seg * 16 + x];
            s += __shfl_xor(s, 1);
            s += __shfl_xor(s, 2);
            if (seg == 0) rqs_w[m * 5 + t] = (s - qq) * 0.125f;
        }
    }

    // Q fragment (B-operand): B[n=q=lane&15][k=quad*8+j]
    v8h aq0 = *(const v8h*)(Qh + (size_t)(qw + n16) * 64 + quad * 8);
    v8h aq1 = *(const v8h*)(Qh + (size_t)(qw + n16) * 64 + 32 + quad * 8);

    __syncthreads();   // drains tile-0 staging; rqs visible (per-wave anyway)

    float rc[5];
    #pragma unroll
    for (int t = 0; t < 5; t++) rc[t] = rqs_w[n16 * 5 + t];

    // bucket sums for this lane's q-row (index = rpk/rpv table row):
    // 4: diff>=2, 3: diff==1, 2: diff==0, 1: diff==-1, 0: diff<=-2
    float bkt[5] = {0.f, 0.f, 0.f, 0.f, 0.f};
    v4f O[4] = {};

    const int pphys0 = quad ^ (n16 & 7);
    const int pphys1 = (quad + 4) ^ (n16 & 7);

    for (int it = 0; it < 16; ++it) {
        const int cur = it & 1;
        const int kb = it * 64;
        if (it + 1 < 16) {                 // prefetch next tile into other buffer
            const int nxt = 1 - cur;
            const int kn = kb + 64;
            #pragma unroll
            for (int p = 0; p < 2; p++) {
                int c = wave * 2 + p;
                int row = c * 8 + rL;
                async_copy16(Qh + (size_t)(kn + row) * 64 + lcs * 8, &Ks[nxt][c * 512]);
                async_copy16(Vh + (size_t)row * 1024 + kn + lcs * 8, &Vs[nxt][c * 512]);
            }
        }

        // ---- scores S^T: lane owns q = qw+n16, k = t*16 + quad*4 + r ----
        #pragma unroll
        for (int t = 0; t < 4; t++) {
            v8h ak0 = *(const v8h*)(&Ks[cur][(t * 16 + n16) * 64 + pphys0 * 8]);
            v8h ak1 = *(const v8h*)(&Ks[cur][(t * 16 + n16) * 64 + pphys1 * 8]);
            v4f s = {0.f, 0.f, 0.f, 0.f};
            s = MFMA_F16(ak0, aq0, s);
            s = MFMA_F16(ak1, aq1, s);
            const int dqt = qw - kb - t * 16;      // wave-uniform
            float pv[4];
            if (dqt >= 32) {                       // whole tile diff >= 2
                #pragma unroll
                for (int r = 0; r < 4; r++) {
                    float p = __expf(fmaf(s[r], 0.125f, rc[4]));
                    pv[r] = p; bkt[4] += p;
                }
            } else if (dqt <= -32) {               // whole tile diff <= -2
                #pragma unroll
                for (int r = 0; r < 4; r++) {
                    float p = __expf(fmaf(s[r], 0.125f, rc[0]));
                    pv[r] = p; bkt[0] += p;
                }
            } else {                               // near-diagonal tile
                #pragma unroll
                for (int r = 0; r < 4; r++) {
                    int diff = dqt + n16 - quad * 4 - r;
                    float rv = diff >= 2  ? rc[4]
                             : diff == 1  ? rc[3]
                             : diff == 0  ? rc[2]
                             : diff == -1 ? rc[1]
                                          : rc[0];
                    float p = __expf(fmaf(s[r], 0.125f, rv));
                    pv[r] = p;
                    bkt[4] += (diff >= 2)  ? p : 0.f;
                    bkt[3] += (diff == 1)  ? p : 0.f;
                    bkt[2] += (diff == 0)  ? p : 0.f;
                    bkt[1] += (diff == -1) ? p : 0.f;
                    bkt[0] += (diff <= -2) ? p : 0.f;
                }
            }
            // P pack: lane holds P[q=n16][k = t*16+quad*4 .. +3] -> one b64 write
            v4h pk = { (_Float16)pv[0], (_Float16)pv[1], (_Float16)pv[2], (_Float16)pv[3] };
            int c16 = t * 2 + (quad >> 1);
            *(v4h*)(&Ps[wave][n16 * 64 + ((c16 ^ (n16 & 7)) << 3) + (quad & 1) * 4]) = pk;
        }

        // P fragments (B-operand): B[n=q=n16][k=quad*8+j]; same-wave DS in-order
        v8h pf0 = *(const v8h*)(&Ps[wave][n16 * 64 + pphys0 * 8]);
        v8h pf1 = *(const v8h*)(&Ps[wave][n16 * 64 + pphys1 * 8]);
        #pragma unroll
        for (int dt = 0; dt < 4; dt++) {
            v8h av0 = *(const v8h*)(&Vs[cur][(dt * 16 + n16) * 64 + pphys0 * 8]);
            v8h av1 = *(const v8h*)(&Vs[cur][(dt * 16 + n16) * 64 + pphys1 * 8]);
            O[dt] = MFMA_F16(av0, pf0, O[dt]);    // O^T: row = d-local, col = q
            O[dt] = MFMA_F16(av1, pf1, O[dt]);
        }

        __syncthreads();   // drains prefetch (flew across compute) + buffer handoff
    }

    // epilogue: reduce buckets across the 4 quads sharing this q-row
    #pragma unroll
    for (int t = 0; t < 5; t++) {
        bkt[t] += __shfl_xor(bkt[t], 16);
        bkt[t] += __shfl_xor(bkt[t], 32);
    }
    float l = bkt[0] + bkt[1] + bkt[2] + bkt[3] + bkt[4];
    float inv = 1.0f / l;
    int q = qw + n16;
    size_t orow = (size_t)((bh >> 4) * 1024 + q) * 1024 + (bh & 15) * 64;
    #pragma unroll
    for (int dt = 0; dt < 4; dt++) {
        int d0 = dt * 16 + quad * 4;
        v4h st;
        #pragma unroll
        for (int r = 0; r < 4; r++) {
            int d = d0 + r;
            float w2 = bkt[4] * rpv[4 * 64 + d] + bkt[3] * rpv[3 * 64 + d]
                     + bkt[2] * rpv[2 * 64 + d] + bkt[1] * rpv[1 * 64 + d]
                     + bkt[0] * rpv[0 * 64 + d];
            st[r] = (_Float16)((O[dt][r] + w2) * inv);
        }
        *(v4h*)(attn_o + orow + d0) = st;
    }
}

// ---------------- host launcher ----------------
extern "C" void kernel_launch(void* const* d_in, const int* in_sizes, int n_in,
                              void* d_out, int out_size, void* d_ws, size_t ws_size,
                              hipStream_t stream)
{
    const float* query = (const float*)d_in[0];
    // d_in[1] = key (unused: reference's k projection is dead code)
    const float* value = (const float*)d_in[2];
    const float* Wq = (const float*)d_in[3];
    const float* bq = (const float*)d_in[4];
    // d_in[5], d_in[6] = Wk, bk (unused)
    const float* Wv = (const float*)d_in[7];
    const float* bv = (const float*)d_in[8];
    const float* Wo = (const float*)d_in[9];
    const float* bo = (const float*)d_in[10];
    const float* rpk = (const float*)d_in[11];
    const float* rpv = (const float*)d_in[12];
    float* out = (float*)d_out;

    char* ws = (char*)d_ws;
    const size_t MB = 1024 * 1024;
    _Float16* q_bhsd = (_Float16*)(ws);             // 8 MB: q proj (B,H,S,D)
    _Float16* v_t    = (_Float16*)(ws + 8 * MB);    // 8 MB: v proj (B,H,D,S)
    _Float16* q16    = (_Float16*)(ws + 16 * MB);   // 8 MB: query fp16
    _Float16* attn_o = (_Float16*)(ws + 16 * MB);   // aliases q16 (dead after gemm_qv)
    _Float16* v16    = (_Float16*)(ws + 24 * MB);   // 8 MB: value fp16
    _Float16* wq16   = (_Float16*)(ws + 32 * MB);   // 2 MB
    _Float16* wv16   = (_Float16*)(ws + 34 * MB);   // 2 MB
    _Float16* wo16   = (_Float16*)(ws + 36 * MB);   // 2 MB   (total 38 MB)

    cvt5_kernel<<<dim3(4096, 5), 256, 0, stream>>>(
        query, value, Wq, Wv, Wo, q16, v16, wq16, wv16, wo16,
        4096 * 1024, 4096 * 1024, 1024 * 1024, 1024 * 1024, 1024 * 1024);

    gemm_qv_kernel<<<dim3(512), 256, 0, stream>>>(
        q16, v16, wq16, wv16, bq, bv, q_bhsd, v_t);

    attn_kernel<<<dim3(1024), 256, 0, stream>>>(q_bhsd, v_t, rpk, rpv, attn_o);

    gemm_o_kernel<<<dim3(512), 256, 0, stream>>>(attn_o, wo16, bo, out);
}